// Round 3
// baseline (325.826 us; speedup 1.0000x reference)
//
#include <hip/hip_runtime.h>
#include <hip/hip_bf16.h>
#include <stdint.h>

typedef __attribute__((ext_vector_type(8))) __bf16 bf16x8;
typedef __attribute__((ext_vector_type(4))) float f32x4;
typedef __hip_bfloat16 bf16_t;

#define T_SEQ 2048
#define D_MODEL 1024
#define N_HEADS 16
#define N_KV 4
#define HD 64
#define LDQKV 1536
#define KDIM 1024

// Convert 16 consecutive fp32 (4x float4) -> 16 bf16 (2x int4)
__device__ inline void cvt16(const float4* __restrict__ g, int4* __restrict__ s) {
  float4 v0 = g[0], v1 = g[1], v2 = g[2], v3 = g[3];
  union { int4 i[2]; __hip_bfloat162 h[8]; } u;
  u.h[0] = __float22bfloat162_rn(make_float2(v0.x, v0.y));
  u.h[1] = __float22bfloat162_rn(make_float2(v0.z, v0.w));
  u.h[2] = __float22bfloat162_rn(make_float2(v1.x, v1.y));
  u.h[3] = __float22bfloat162_rn(make_float2(v1.z, v1.w));
  u.h[4] = __float22bfloat162_rn(make_float2(v2.x, v2.y));
  u.h[5] = __float22bfloat162_rn(make_float2(v2.z, v2.w));
  u.h[6] = __float22bfloat162_rn(make_float2(v3.x, v3.y));
  u.h[7] = __float22bfloat162_rn(make_float2(v3.z, v3.w));
  s[0] = u.i[0]; s[1] = u.i[1];
}

__device__ inline void storeC(bf16_t* p, float v) { *p = __float2bfloat16(v); }
__device__ inline void storeC(float* p, float v) { *p = v; }

// ---------------------------------------------------------------------------
// GEMM: C[m0+row, n0+col] = sum_k A[m0+row, k] * W[nr0+col, k]
// A: (M x 1024) row-major, fp32 (A_F32=true) or bf16. W: fp32, rows = output
// features (B^T layout). fp32 operands are converted to bf16 during LDS
// staging. 128x128 tile, BK=32, 4 waves (2x2), 4x4 16x16x32 MFMA frags/wave.
// CT: output element type (bf16 for intermediates, float for final output).
// ---------------------------------------------------------------------------
template <bool A_F32, typename CT>
__global__ __launch_bounds__(256) void gemm_bt(
    const void* __restrict__ Ap,
    const float* __restrict__ W0, const float* __restrict__ W1,
    const float* __restrict__ W2,
    CT* __restrict__ C, const int ldC)
{
  __shared__ bf16_t As[128 * 32];
  __shared__ bf16_t Bs[128 * 32];
  const int tid = threadIdx.x;
  const int lane = tid & 63;
  const int wv = tid >> 6;
  const int wr = wv >> 1, wc = wv & 1;
  const int m0 = blockIdx.y * 128;
  const int n0 = blockIdx.x * 128;
  const float* W = W0; int nr0 = n0;
  if (n0 >= 1280)      { W = W2; nr0 = n0 - 1280; }
  else if (n0 >= 1024) { W = W1; nr0 = n0 - 1024; }

  const int ra = tid >> 1;            // 0..127: tile row this thread stages
  const int ca = (tid & 1) * 16;      // 0 or 16: k-column half
  const float*  paf = (const float*)Ap  + (size_t)(m0 + ra) * KDIM + ca;
  const bf16_t* pah = (const bf16_t*)Ap + (size_t)(m0 + ra) * KDIM + ca;
  const float*  pb  = W + (size_t)(nr0 + ra) * KDIM + ca;
  int4* sa = (int4*)(&As[ra * 32 + ca]);
  int4* sb = (int4*)(&Bs[ra * 32 + ca]);

  f32x4 acc[4][4];
#pragma unroll
  for (int m = 0; m < 4; ++m)
#pragma unroll
    for (int n = 0; n < 4; ++n)
      acc[m][n] = {0.f, 0.f, 0.f, 0.f};

  const int fr = lane & 15;
  const int fq = lane >> 4;

  for (int k0 = 0; k0 < KDIM; k0 += 32) {
    if constexpr (A_F32) {
      cvt16((const float4*)(paf + k0), sa);
    } else {
      const int4* ga = (const int4*)(pah + k0);
      int4 a0 = ga[0], a1 = ga[1];
      sa[0] = a0; sa[1] = a1;
    }
    cvt16((const float4*)(pb + k0), sb);
    __syncthreads();
    bf16x8 af[4], bfv[4];
#pragma unroll
    for (int m = 0; m < 4; ++m)
      af[m] = *(const bf16x8*)(&As[(wr * 64 + m * 16 + fr) * 32 + fq * 8]);
#pragma unroll
    for (int n = 0; n < 4; ++n)
      bfv[n] = *(const bf16x8*)(&Bs[(wc * 64 + n * 16 + fr) * 32 + fq * 8]);
#pragma unroll
    for (int m = 0; m < 4; ++m)
#pragma unroll
      for (int n = 0; n < 4; ++n)
        acc[m][n] = __builtin_amdgcn_mfma_f32_16x16x32_bf16(af[m], bfv[n],
                                                            acc[m][n], 0, 0, 0);
    __syncthreads();
  }

  // C/D layout: col = lane&15, row = (lane>>4)*4 + reg  [guide §3, m89/m91]
#pragma unroll
  for (int m = 0; m < 4; ++m)
#pragma unroll
    for (int n = 0; n < 4; ++n)
#pragma unroll
      for (int r = 0; r < 4; ++r) {
        const int row = wr * 64 + m * 16 + fq * 4 + r;
        const int col = wc * 64 + n * 16 + fr;
        storeC(&C[(size_t)(m0 + row) * ldC + n0 + col], acc[m][n][r]);
      }
}

// ---------------------------------------------------------------------------
// RMSNorm (per head of 64 dims) + RoPE (first 32 dims) in-place on q,k parts.
// One block per (b,t) row; wave handles one head at a time (lane = dim).
// cos/sin/scales are fp32.
// ---------------------------------------------------------------------------
__global__ __launch_bounds__(256) void rms_rope(
    bf16_t* __restrict__ qkv, const float* __restrict__ cosb,
    const float* __restrict__ sinb, const float* __restrict__ qs,
    const float* __restrict__ ks)
{
  const int row = blockIdx.x;
  const int t = row & (T_SEQ - 1);
  const int tid = threadIdx.x;
  const int lane = tid & 63;
  const int wv = tid >> 6;
  const int f = lane & 15;
  const float c = (lane < 32) ? cosb[t * 16 + f] : 0.f;
  const float s = (lane < 32) ? sinb[t * 16 + f] : 0.f;
  for (int hh = wv; hh < 20; hh += 4) {   // heads 0..15 = q, 16..19 = k
    const size_t idx = (size_t)row * LDQKV + hh * 64 + lane;
    const float v = __bfloat162float(qkv[idx]);
    float ssum = v * v;
#pragma unroll
    for (int off = 32; off; off >>= 1) ssum += __shfl_xor(ssum, off);
    const float norm = rsqrtf(ssum * (1.f / 64.f) + 1e-6f);
    const float scale = (hh < 16 ? qs : ks)[lane];
    float val = v * norm * scale;
    const float partner = __shfl_xor(val, 16);
    if (lane < 16)      val = val * c - partner * s;       // x1' = x1*c - x2*s
    else if (lane < 32) val = partner * s + val * c;       // x2' = x1*s + x2*c
    qkv[idx] = __float2bfloat16(val);
  }
}

// ---------------------------------------------------------------------------
// V transpose: qkv v-part (t-major) -> v_t[(b*4+kvh)*64 + d][t]  (t contiguous)
// so attention PV B-fragments are 16B-contiguous global reads.
// ---------------------------------------------------------------------------
__global__ __launch_bounds__(256) void v_transpose(
    const bf16_t* __restrict__ qkv, bf16_t* __restrict__ v_t)
{
  __shared__ bf16_t tile[64 * 72];        // [t][d], pad 72 for alignment/banks
  const int g = blockIdx.x;               // b*4 + kvh
  const int t0 = blockIdx.y * 64;
  const int tid = threadIdx.x;
  const int i = tid >> 2;                 // 0..63
  const int dc = (tid & 3) * 16;          // 0,16,32,48
  const bf16_t* src = qkv + (size_t)((g >> 2) * T_SEQ + t0 + i) * LDQKV
                      + 1280 + (g & 3) * HD + dc;
  const int4* gs = (const int4*)src;
  int4 x0 = gs[0], x1 = gs[1];
  int4* st = (int4*)(&tile[i * 72 + dc]);
  st[0] = x0; st[1] = x1;
  __syncthreads();
  union { int4 v[2]; bf16_t h[16]; } u;
#pragma unroll
  for (int j = 0; j < 16; ++j) u.h[j] = tile[(dc + j) * 72 + i];
  int4* dst = (int4*)(v_t + (size_t)(g * HD + i) * T_SEQ + t0 + dc);
  dst[0] = u.v[0]; dst[1] = u.v[1];
}

// ---------------------------------------------------------------------------
// Causal GQA flash attention. Block = (q-tile of 64 rows, (b,h)). 4 waves;
// wave w owns k/d column strip w*16..w*16+15. Q frags hoisted to registers;
// K and V fragments read directly from global (L2-resident). Online softmax
// through LDS (S fp32, P bf16). 2 barriers per k-tile.
// ---------------------------------------------------------------------------
__global__ __launch_bounds__(256) void attn(
    const bf16_t* __restrict__ qkv, const bf16_t* __restrict__ v_t,
    bf16_t* __restrict__ y)
{
  __shared__ float S_lds[64 * 65];
  __shared__ bf16_t P_lds[64 * 72];
  __shared__ float rowf[64];
  const int tid = threadIdx.x;
  const int lane = tid & 63;
  const int wv = tid >> 6;
  const int fr = lane & 15;
  const int fq = lane >> 4;
  const int qt = blockIdx.x;
  const int bh = blockIdx.y;
  const int b = bh >> 4, h = bh & 15, kvh = h >> 2;
  const int q0 = qt * 64;

  bf16x8 qf[4][2];
#pragma unroll
  for (int m = 0; m < 4; ++m)
#pragma unroll
    for (int kd = 0; kd < 2; ++kd)
      qf[m][kd] = *(const bf16x8*)(qkv
          + (size_t)(b * T_SEQ + q0 + m * 16 + fr) * LDQKV
          + h * HD + kd * 32 + fq * 8);

  f32x4 acc[4];
#pragma unroll
  for (int m = 0; m < 4; ++m) acc[m] = {0.f, 0.f, 0.f, 0.f};

  float m_run = -1e30f, l_run = 0.f;
  const int srow = tid >> 2, sc = tid & 3;   // softmax: 4 threads per q-row

  for (int kt = 0; kt <= qt; ++kt) {
    const int k0 = kt * 64;
    bf16x8 kf[2];
#pragma unroll
    for (int kd = 0; kd < 2; ++kd)
      kf[kd] = *(const bf16x8*)(qkv
          + (size_t)(b * T_SEQ + k0 + wv * 16 + fr) * LDQKV
          + 1024 + kvh * HD + kd * 32 + fq * 8);
    f32x4 sfr[4];
#pragma unroll
    for (int m = 0; m < 4; ++m) {
      f32x4 z = {0.f, 0.f, 0.f, 0.f};
      z = __builtin_amdgcn_mfma_f32_16x16x32_bf16(qf[m][0], kf[0], z, 0, 0, 0);
      sfr[m] = __builtin_amdgcn_mfma_f32_16x16x32_bf16(qf[m][1], kf[1], z, 0, 0, 0);
    }
#pragma unroll
    for (int m = 0; m < 4; ++m)
#pragma unroll
      for (int r = 0; r < 4; ++r) {
        const int qrow = m * 16 + fq * 4 + r;
        const int kcol = wv * 16 + fr;
        float sv = sfr[m][r] * 0.125f;            // 1/sqrt(64)
        if (k0 + kcol > q0 + qrow) sv = -1e30f;   // causal mask
        S_lds[qrow * 65 + kcol] = sv;
      }
    __syncthreads();

    // online softmax for this tile
    float svv[16];
    float mloc = -1e30f;
#pragma unroll
    for (int i = 0; i < 16; ++i) {
      svv[i] = S_lds[srow * 65 + sc * 16 + i];
      mloc = fmaxf(mloc, svv[i]);
    }
    mloc = fmaxf(mloc, __shfl_xor(mloc, 1));
    mloc = fmaxf(mloc, __shfl_xor(mloc, 2));
    const float mnew = fmaxf(m_run, mloc);
    const float corr = __expf(m_run - mnew);
    float lsum = 0.f;
#pragma unroll
    for (int i = 0; i < 16; ++i) {
      const float p = __expf(svv[i] - mnew);
      lsum += p;
      P_lds[srow * 72 + sc * 16 + i] = __float2bfloat16(p);
    }
    lsum += __shfl_xor(lsum, 1);
    lsum += __shfl_xor(lsum, 2);
    l_run = l_run * corr + lsum;
    m_run = mnew;
    if (sc == 0) rowf[srow] = corr;
    __syncthreads();

    // rescale accumulator + PV
#pragma unroll
    for (int m = 0; m < 4; ++m)
#pragma unroll
      for (int r = 0; r < 4; ++r)
        acc[m][r] *= rowf[m * 16 + fq * 4 + r];
    bf16x8 bv[2];
#pragma unroll
    for (int kkf = 0; kkf < 2; ++kkf)
      bv[kkf] = *(const bf16x8*)(v_t
          + (size_t)((b * N_KV + kvh) * HD + wv * 16 + fr) * T_SEQ
          + k0 + kkf * 32 + fq * 8);
#pragma unroll
    for (int m = 0; m < 4; ++m) {
      bf16x8 pa0 = *(const bf16x8*)(&P_lds[(m * 16 + fr) * 72 + fq * 8]);
      acc[m] = __builtin_amdgcn_mfma_f32_16x16x32_bf16(pa0, bv[0], acc[m], 0, 0, 0);
      bf16x8 pa1 = *(const bf16x8*)(&P_lds[(m * 16 + fr) * 72 + 32 + fq * 8]);
      acc[m] = __builtin_amdgcn_mfma_f32_16x16x32_bf16(pa1, bv[1], acc[m], 0, 0, 0);
    }
    // no trailing barrier needed: this iter's P/rowf reads complete before any
    // thread can pass the NEXT iter's first barrier (which fences S/P writes).
  }

  __syncthreads();
  if (sc == 0) rowf[srow] = 1.f / l_run;
  __syncthreads();
#pragma unroll
  for (int m = 0; m < 4; ++m)
#pragma unroll
    for (int r = 0; r < 4; ++r) {
      const int row = m * 16 + fq * 4 + r;
      const float o = acc[m][r] * rowf[row];
      y[(size_t)(b * T_SEQ + q0 + row) * D_MODEL + h * HD + wv * 16 + fr] =
          __float2bfloat16(o);
    }
}

// ---------------------------------------------------------------------------
extern "C" void kernel_launch(void* const* d_in, const int* in_sizes, int n_in,
                              void* d_out, int out_size, void* d_ws,
                              size_t ws_size, hipStream_t stream) {
  const float* x    = (const float*)d_in[0];
  const float* cosb = (const float*)d_in[1];
  const float* sinb = (const float*)d_in[2];
  const float* Wq   = (const float*)d_in[3];
  const float* Wk   = (const float*)d_in[4];
  const float* Wv   = (const float*)d_in[5];
  const float* Wo   = (const float*)d_in[6];
  const float* qs   = (const float*)d_in[7];
  const float* ks   = (const float*)d_in[8];
  float* out = (float*)d_out;   // reference output dtype is float32

  char* ws = (char*)d_ws;
  bf16_t* qkv = (bf16_t*)ws;                                   // 8192*1536*2 = 25165824 B
  bf16_t* v_t = (bf16_t*)(ws + 25165824);                      // 16*64*2048*2 = 4194304 B
  bf16_t* y   = (bf16_t*)(ws + 25165824 + 4194304);            // 8192*1024*2 = 16777216 B

  // 1. fused QKV projection: qkv[8192][1536]  (fp32 x, fp32 W -> bf16)
  gemm_bt<true, bf16_t><<<dim3(12, 64), 256, 0, stream>>>(x, Wq, Wk, Wv, qkv, LDQKV);
  // 2. RMSNorm + RoPE in-place on q,k
  rms_rope<<<dim3(8192), 256, 0, stream>>>(qkv, cosb, sinb, qs, ks);
  // 3. V transpose for PV fragment reads
  v_transpose<<<dim3(16, 32), 256, 0, stream>>>(qkv, v_t);
  // 4. causal GQA flash attention -> y[8192][1024] (bf16)
  attn<<<dim3(32, 64), 256, 0, stream>>>(qkv, v_t, y);
  // 5. output projection (bf16 y, fp32 Wo -> fp32 out)
  gemm_bt<false, float><<<dim3(8, 64), 256, 0, stream>>>(y, Wo, Wo, Wo, out, D_MODEL);
}

// Round 4
// 260.605 us; speedup vs baseline: 1.2503x; 1.2503x over previous
//
#include <hip/hip_runtime.h>
#include <hip/hip_bf16.h>
#include <stdint.h>

typedef __attribute__((ext_vector_type(8)))  __bf16 bf16x8;
typedef __attribute__((ext_vector_type(4)))  float  f32x4;
typedef __attribute__((ext_vector_type(16))) float  f32x16;
typedef __hip_bfloat16 bf16_t;

#define T_SEQ 2048
#define D_MODEL 1024
#define N_HEADS 16
#define N_KV 4
#define HD 64
#define LDQKV 1536
#define KDIM 1024

// Convert 16 consecutive fp32 (4x float4) -> 16 bf16 (2x int4)
__device__ inline void cvt16(const float4* __restrict__ g, int4* __restrict__ s) {
  float4 v0 = g[0], v1 = g[1], v2 = g[2], v3 = g[3];
  union { int4 i[2]; __hip_bfloat162 h[8]; } u;
  u.h[0] = __float22bfloat162_rn(make_float2(v0.x, v0.y));
  u.h[1] = __float22bfloat162_rn(make_float2(v0.z, v0.w));
  u.h[2] = __float22bfloat162_rn(make_float2(v1.x, v1.y));
  u.h[3] = __float22bfloat162_rn(make_float2(v1.z, v1.w));
  u.h[4] = __float22bfloat162_rn(make_float2(v2.x, v2.y));
  u.h[5] = __float22bfloat162_rn(make_float2(v2.z, v2.w));
  u.h[6] = __float22bfloat162_rn(make_float2(v3.x, v3.y));
  u.h[7] = __float22bfloat162_rn(make_float2(v3.z, v3.w));
  s[0] = u.i[0]; s[1] = u.i[1];
}

__device__ inline void storeC(bf16_t* p, float v) { *p = __float2bfloat16(v); }
__device__ inline void storeC(float* p, float v) { *p = v; }

// ---------------------------------------------------------------------------
// GEMM: C[m0+row, n0+col] = sum_k A[m0+row, k] * W[nr0+col, k]
// (unchanged from round 3 — passing)
// ---------------------------------------------------------------------------
template <bool A_F32, typename CT>
__global__ __launch_bounds__(256) void gemm_bt(
    const void* __restrict__ Ap,
    const float* __restrict__ W0, const float* __restrict__ W1,
    const float* __restrict__ W2,
    CT* __restrict__ C, const int ldC)
{
  __shared__ bf16_t As[128 * 32];
  __shared__ bf16_t Bs[128 * 32];
  const int tid = threadIdx.x;
  const int lane = tid & 63;
  const int wv = tid >> 6;
  const int wr = wv >> 1, wc = wv & 1;
  const int m0 = blockIdx.y * 128;
  const int n0 = blockIdx.x * 128;
  const float* W = W0; int nr0 = n0;
  if (n0 >= 1280)      { W = W2; nr0 = n0 - 1280; }
  else if (n0 >= 1024) { W = W1; nr0 = n0 - 1024; }

  const int ra = tid >> 1;
  const int ca = (tid & 1) * 16;
  const float*  paf = (const float*)Ap  + (size_t)(m0 + ra) * KDIM + ca;
  const bf16_t* pah = (const bf16_t*)Ap + (size_t)(m0 + ra) * KDIM + ca;
  const float*  pb  = W + (size_t)(nr0 + ra) * KDIM + ca;
  int4* sa = (int4*)(&As[ra * 32 + ca]);
  int4* sb = (int4*)(&Bs[ra * 32 + ca]);

  f32x4 acc[4][4];
#pragma unroll
  for (int m = 0; m < 4; ++m)
#pragma unroll
    for (int n = 0; n < 4; ++n)
      acc[m][n] = {0.f, 0.f, 0.f, 0.f};

  const int fr = lane & 15;
  const int fq = lane >> 4;

  for (int k0 = 0; k0 < KDIM; k0 += 32) {
    if constexpr (A_F32) {
      cvt16((const float4*)(paf + k0), sa);
    } else {
      const int4* ga = (const int4*)(pah + k0);
      int4 a0 = ga[0], a1 = ga[1];
      sa[0] = a0; sa[1] = a1;
    }
    cvt16((const float4*)(pb + k0), sb);
    __syncthreads();
    bf16x8 af[4], bfv[4];
#pragma unroll
    for (int m = 0; m < 4; ++m)
      af[m] = *(const bf16x8*)(&As[(wr * 64 + m * 16 + fr) * 32 + fq * 8]);
#pragma unroll
    for (int n = 0; n < 4; ++n)
      bfv[n] = *(const bf16x8*)(&Bs[(wc * 64 + n * 16 + fr) * 32 + fq * 8]);
#pragma unroll
    for (int m = 0; m < 4; ++m)
#pragma unroll
      for (int n = 0; n < 4; ++n)
        acc[m][n] = __builtin_amdgcn_mfma_f32_16x16x32_bf16(af[m], bfv[n],
                                                            acc[m][n], 0, 0, 0);
    __syncthreads();
  }

#pragma unroll
  for (int m = 0; m < 4; ++m)
#pragma unroll
    for (int n = 0; n < 4; ++n)
#pragma unroll
      for (int r = 0; r < 4; ++r) {
        const int row = wr * 64 + m * 16 + fq * 4 + r;
        const int col = wc * 64 + n * 16 + fr;
        storeC(&C[(size_t)(m0 + row) * ldC + n0 + col], acc[m][n][r]);
      }
}

// ---------------------------------------------------------------------------
// RMSNorm + RoPE (unchanged from round 3 — passing)
// ---------------------------------------------------------------------------
__global__ __launch_bounds__(256) void rms_rope(
    bf16_t* __restrict__ qkv, const float* __restrict__ cosb,
    const float* __restrict__ sinb, const float* __restrict__ qs,
    const float* __restrict__ ks)
{
  const int row = blockIdx.x;
  const int t = row & (T_SEQ - 1);
  const int tid = threadIdx.x;
  const int lane = tid & 63;
  const int wv = tid >> 6;
  const int f = lane & 15;
  const float c = (lane < 32) ? cosb[t * 16 + f] : 0.f;
  const float s = (lane < 32) ? sinb[t * 16 + f] : 0.f;
  for (int hh = wv; hh < 20; hh += 4) {
    const size_t idx = (size_t)row * LDQKV + hh * 64 + lane;
    const float v = __bfloat162float(qkv[idx]);
    float ssum = v * v;
#pragma unroll
    for (int off = 32; off; off >>= 1) ssum += __shfl_xor(ssum, off);
    const float norm = rsqrtf(ssum * (1.f / 64.f) + 1e-6f);
    const float scale = (hh < 16 ? qs : ks)[lane];
    float val = v * norm * scale;
    const float partner = __shfl_xor(val, 16);
    if (lane < 16)      val = val * c - partner * s;
    else if (lane < 32) val = partner * s + val * c;
    qkv[idx] = __float2bfloat16(val);
  }
}

// ---------------------------------------------------------------------------
// V transpose (unchanged from round 3 — passing)
// ---------------------------------------------------------------------------
__global__ __launch_bounds__(256) void v_transpose(
    const bf16_t* __restrict__ qkv, bf16_t* __restrict__ v_t)
{
  __shared__ bf16_t tile[64 * 72];
  const int g = blockIdx.x;
  const int t0 = blockIdx.y * 64;
  const int tid = threadIdx.x;
  const int i = tid >> 2;
  const int dc = (tid & 3) * 16;
  const bf16_t* src = qkv + (size_t)((g >> 2) * T_SEQ + t0 + i) * LDQKV
                      + 1280 + (g & 3) * HD + dc;
  const int4* gs = (const int4*)src;
  int4 x0 = gs[0], x1 = gs[1];
  int4* st = (int4*)(&tile[i * 72 + dc]);
  st[0] = x0; st[1] = x1;
  __syncthreads();
  union { int4 v[2]; bf16_t h[16]; } u;
#pragma unroll
  for (int j = 0; j < 16; ++j) u.h[j] = tile[(dc + j) * 72 + i];
  int4* dst = (int4*)(v_t + (size_t)(g * HD + i) * T_SEQ + t0 + dc);
  dst[0] = u.v[0]; dst[1] = u.v[1];
}

// ---------------------------------------------------------------------------
// Causal GQA flash attention v2 — swapped-operand, barrier-free, LDS-free.
// Wave owns 32 q-rows (lane&31 = q); S^T = mfma_32x32x16(K, Q) puts a full
// 32-k strip for lane's q in 16 regs (+ partner lane via shfl_xor 32).
// Softmax fully in-register (log2 domain). P^T rebuilt as PV B-operand via
// cvt_pk + 8 dword shfl_xor(32). O^T = mfma(V^T, P^T) keeps rescale
// lane-local. 4 waves/block = 128 q rows; grid (bh=64, qb=16 reversed so
// longest blocks dispatch first). K/V read direct from L2.
// ---------------------------------------------------------------------------
__global__ __launch_bounds__(256) void attn(
    const bf16_t* __restrict__ qkv, const bf16_t* __restrict__ v_t,
    bf16_t* __restrict__ y)
{
  const int tid  = threadIdx.x;
  const int lane = tid & 63;
  const int wv   = tid >> 6;
  const int ql   = lane & 31;      // q within wave strip; also d_local for V
  const int hi   = lane >> 5;      // half-wave index
  const int bh   = blockIdx.x;
  const int b = bh >> 4, h = bh & 15, kvh = h >> 2;
  const int qb   = 15 - (int)blockIdx.y;   // longest first
  const int q0w  = qb * 128 + wv * 32;
  const int q_glob = q0w + ql;
  const float SCALE_LOG2 = 0.125f * 1.44269504089f;  // 1/sqrt(64) * log2(e)

  // Q fragments (B-operand): lane holds Q[q=ql][c*16 + hi*8 + j], j=0..7
  const bf16_t* Qrow = qkv + (size_t)(b * T_SEQ + q_glob) * LDQKV + h * HD + hi * 8;
  bf16x8 qfrag[4];
#pragma unroll
  for (int c = 0; c < 4; ++c)
    qfrag[c] = *(const bf16x8*)(Qrow + c * 16);

  // K base: lane's k-row = ql within tile; advance tile by += 32*LDQKV
  const bf16_t* Kp = qkv + ((size_t)(b * T_SEQ + ql)) * LDQKV + 1024 + kvh * HD + hi * 8;
  // V base (v_t layout [g*64+d][t]): lane's d_local = ql; +k0 per tile
  const bf16_t* Vb = v_t + (size_t)((b * N_KV + kvh) * HD + ql) * T_SEQ + hi * 8;

  f32x16 acc0, acc1;
#pragma unroll
  for (int i = 0; i < 16; ++i) { acc0[i] = 0.f; acc1[i] = 0.f; }
  float m_run = -1e30f, l_run = 0.f;

  const int nfull = q0w >> 5;           // full (unmasked) 32-k tiles
  for (int kt = 0; kt <= nfull; ++kt) {
    const int k0 = kt << 5;
    const bool masked = (kt == nfull);

    // --- K loads + V loads (issue early), QK^T ---
    bf16x8 kf[4];
#pragma unroll
    for (int c = 0; c < 4; ++c)
      kf[c] = *(const bf16x8*)(Kp + (size_t)k0 * LDQKV + c * 16);
    const bf16_t* Vp = Vb + k0;
    bf16x8 v00 = *(const bf16x8*)(Vp);
    bf16x8 v01 = *(const bf16x8*)(Vp + 16);
    bf16x8 v10 = *(const bf16x8*)(Vp + (size_t)32 * T_SEQ);
    bf16x8 v11 = *(const bf16x8*)(Vp + (size_t)32 * T_SEQ + 16);

    f32x16 st;
#pragma unroll
    for (int i = 0; i < 16; ++i) st[i] = 0.f;
#pragma unroll
    for (int c = 0; c < 4; ++c)
      st = __builtin_amdgcn_mfma_f32_32x32x16_bf16(kf[c], qfrag[c], st, 0, 0, 0);

    // --- softmax (in-register, log2 domain) ---
    // lane's S^T reg r: k = k0 + (r&3) + 8*(r>>2) + 4*hi, q = q_glob
    float sreg[16];
#pragma unroll
    for (int r = 0; r < 16; ++r) sreg[r] = st[r] * SCALE_LOG2;
    if (masked) {
#pragma unroll
      for (int r = 0; r < 16; ++r) {
        const int kg = k0 + (r & 3) + 8 * (r >> 2) + 4 * hi;
        if (kg > q_glob) sreg[r] = -1e30f;
      }
    }
    float smax = sreg[0];
#pragma unroll
    for (int r = 1; r < 16; ++r) smax = fmaxf(smax, sreg[r]);
    smax = fmaxf(smax, __shfl_xor(smax, 32));
    const float mnew = fmaxf(m_run, smax);
    const float corr = exp2f(m_run - mnew);
    float p[16];
    float lsum = 0.f;
#pragma unroll
    for (int r = 0; r < 16; ++r) { p[r] = exp2f(sreg[r] - mnew); lsum += p[r]; }
    lsum += __shfl_xor(lsum, 32);
    l_run = l_run * corr + lsum;
    m_run = mnew;
#pragma unroll
    for (int i = 0; i < 16; ++i) { acc0[i] *= corr; acc1[i] *= corr; }

    // --- pack P^T B-fragments: lane needs P[q, chunk*16 + 8*hi + j] ---
    unsigned int w[8], xw[8];
    union pk { __hip_bfloat162 h2; unsigned int u; };
#pragma unroll
    for (int i = 0; i < 8; ++i) {
      pk t; t.h2 = __float22bfloat162_rn(make_float2(p[2 * i], p[2 * i + 1]));
      w[i] = t.u;
    }
#pragma unroll
    for (int i = 0; i < 8; ++i) xw[i] = __shfl_xor(w[i], 32);
    union fu { unsigned int u[4]; bf16x8 v; };
    fu f1, f2;
    f1.u[0] = hi ? xw[2] : w[0];
    f1.u[1] = hi ? xw[3] : w[1];
    f1.u[2] = hi ? w[2]  : xw[0];
    f1.u[3] = hi ? w[3]  : xw[1];
    f2.u[0] = hi ? xw[6] : w[4];
    f2.u[1] = hi ? xw[7] : w[5];
    f2.u[2] = hi ? w[6]  : xw[4];
    f2.u[3] = hi ? w[7]  : xw[5];

    // --- PV: O^T accumulate (A = V^T rows d, B = P^T) ---
    acc0 = __builtin_amdgcn_mfma_f32_32x32x16_bf16(v00, f1.v, acc0, 0, 0, 0);
    acc0 = __builtin_amdgcn_mfma_f32_32x32x16_bf16(v01, f2.v, acc0, 0, 0, 0);
    acc1 = __builtin_amdgcn_mfma_f32_32x32x16_bf16(v10, f1.v, acc1, 0, 0, 0);
    acc1 = __builtin_amdgcn_mfma_f32_32x32x16_bf16(v11, f2.v, acc1, 0, 0, 0);
  }

  // --- epilogue: O = acc / l_run; lane holds q=q_glob, d = (r&3)+8*(r>>2)+4hi ---
  const float inv = 1.f / l_run;
  bf16_t* yrow = y + (size_t)(b * T_SEQ + q_glob) * D_MODEL + h * HD;
  union st8 { uint2 u2; __hip_bfloat162 h2[2]; };
#pragma unroll
  for (int gg = 0; gg < 4; ++gg) {
    st8 o0, o1;
    o0.h2[0] = __float22bfloat162_rn(make_float2(acc0[4 * gg + 0] * inv, acc0[4 * gg + 1] * inv));
    o0.h2[1] = __float22bfloat162_rn(make_float2(acc0[4 * gg + 2] * inv, acc0[4 * gg + 3] * inv));
    o1.h2[0] = __float22bfloat162_rn(make_float2(acc1[4 * gg + 0] * inv, acc1[4 * gg + 1] * inv));
    o1.h2[1] = __float22bfloat162_rn(make_float2(acc1[4 * gg + 2] * inv, acc1[4 * gg + 3] * inv));
    *(uint2*)(yrow + 8 * gg + 4 * hi)      = o0.u2;
    *(uint2*)(yrow + 32 + 8 * gg + 4 * hi) = o1.u2;
  }
}

// ---------------------------------------------------------------------------
extern "C" void kernel_launch(void* const* d_in, const int* in_sizes, int n_in,
                              void* d_out, int out_size, void* d_ws,
                              size_t ws_size, hipStream_t stream) {
  const float* x    = (const float*)d_in[0];
  const float* cosb = (const float*)d_in[1];
  const float* sinb = (const float*)d_in[2];
  const float* Wq   = (const float*)d_in[3];
  const float* Wk   = (const float*)d_in[4];
  const float* Wv   = (const float*)d_in[5];
  const float* Wo   = (const float*)d_in[6];
  const float* qs   = (const float*)d_in[7];
  const float* ks   = (const float*)d_in[8];
  float* out = (float*)d_out;   // reference output dtype is float32

  char* ws = (char*)d_ws;
  bf16_t* qkv = (bf16_t*)ws;                                   // 25165824 B
  bf16_t* v_t = (bf16_t*)(ws + 25165824);                      // 4194304 B
  bf16_t* y   = (bf16_t*)(ws + 25165824 + 4194304);            // 16777216 B

  gemm_bt<true, bf16_t><<<dim3(12, 64), 256, 0, stream>>>(x, Wq, Wk, Wv, qkv, LDQKV);
  rms_rope<<<dim3(8192), 256, 0, stream>>>(qkv, cosb, sinb, qs, ks);
  v_transpose<<<dim3(16, 32), 256, 0, stream>>>(qkv, v_t);
  attn<<<dim3(64, 16), 256, 0, stream>>>(qkv, v_t, y);
  gemm_bt<false, float><<<dim3(8, 64), 256, 0, stream>>>(y, Wo, Wo, Wo, out, D_MODEL);
}

// Round 6
// 259.667 us; speedup vs baseline: 1.2548x; 1.0036x over previous
//
#include <hip/hip_runtime.h>
#include <hip/hip_bf16.h>
#include <stdint.h>

typedef __attribute__((ext_vector_type(8)))  __bf16 bf16x8;
typedef __attribute__((ext_vector_type(4)))  float  f32x4;
typedef __attribute__((ext_vector_type(16))) float  f32x16;
typedef __hip_bfloat16 bf16_t;

#define T_SEQ 2048
#define D_MODEL 1024
#define N_HEADS 16
#define N_KV 4
#define HD 64
#define LDQKV 1536
#define KDIM 1024

// Convert 16 consecutive fp32 (4x float4) -> 16 bf16 (2x int4)
__device__ inline void cvt16(const float4* __restrict__ g, int4* __restrict__ s) {
  float4 v0 = g[0], v1 = g[1], v2 = g[2], v3 = g[3];
  union { int4 i[2]; __hip_bfloat162 h[8]; } u;
  u.h[0] = __float22bfloat162_rn(make_float2(v0.x, v0.y));
  u.h[1] = __float22bfloat162_rn(make_float2(v0.z, v0.w));
  u.h[2] = __float22bfloat162_rn(make_float2(v1.x, v1.y));
  u.h[3] = __float22bfloat162_rn(make_float2(v1.z, v1.w));
  u.h[4] = __float22bfloat162_rn(make_float2(v2.x, v2.y));
  u.h[5] = __float22bfloat162_rn(make_float2(v2.z, v2.w));
  u.h[6] = __float22bfloat162_rn(make_float2(v3.x, v3.y));
  u.h[7] = __float22bfloat162_rn(make_float2(v3.z, v3.w));
  s[0] = u.i[0]; s[1] = u.i[1];
}

__device__ inline void storeC(bf16_t* p, float v) { *p = __float2bfloat16(v); }
__device__ inline void storeC(float* p, float v) { *p = v; }

// v_permlane32_swap_b32 vdst, vsrc: exchanges vdst.lanes[32:63] with
// vsrc.lanes[0:31]. After plswap(a,b): a = {a_L, b_L}, b = {a_U, b_U}
// (lane-moving: b's lane i value lands in a's lane i+32).
// Register-only op; data deps order it correctly (no memory hazard).
__device__ inline void plswap(unsigned& a, unsigned& b) {
  asm volatile("v_permlane32_swap_b32 %0, %1" : "+v"(a), "+v"(b));
}

// ---------------------------------------------------------------------------
// GEMM (unchanged — passing)
// ---------------------------------------------------------------------------
template <bool A_F32, typename CT>
__global__ __launch_bounds__(256) void gemm_bt(
    const void* __restrict__ Ap,
    const float* __restrict__ W0, const float* __restrict__ W1,
    const float* __restrict__ W2,
    CT* __restrict__ C, const int ldC)
{
  __shared__ bf16_t As[128 * 32];
  __shared__ bf16_t Bs[128 * 32];
  const int tid = threadIdx.x;
  const int lane = tid & 63;
  const int wv = tid >> 6;
  const int wr = wv >> 1, wc = wv & 1;
  const int m0 = blockIdx.y * 128;
  const int n0 = blockIdx.x * 128;
  const float* W = W0; int nr0 = n0;
  if (n0 >= 1280)      { W = W2; nr0 = n0 - 1280; }
  else if (n0 >= 1024) { W = W1; nr0 = n0 - 1024; }

  const int ra = tid >> 1;
  const int ca = (tid & 1) * 16;
  const float*  paf = (const float*)Ap  + (size_t)(m0 + ra) * KDIM + ca;
  const bf16_t* pah = (const bf16_t*)Ap + (size_t)(m0 + ra) * KDIM + ca;
  const float*  pb  = W + (size_t)(nr0 + ra) * KDIM + ca;
  int4* sa = (int4*)(&As[ra * 32 + ca]);
  int4* sb = (int4*)(&Bs[ra * 32 + ca]);

  f32x4 acc[4][4];
#pragma unroll
  for (int m = 0; m < 4; ++m)
#pragma unroll
    for (int n = 0; n < 4; ++n)
      acc[m][n] = {0.f, 0.f, 0.f, 0.f};

  const int fr = lane & 15;
  const int fq = lane >> 4;

  for (int k0 = 0; k0 < KDIM; k0 += 32) {
    if constexpr (A_F32) {
      cvt16((const float4*)(paf + k0), sa);
    } else {
      const int4* ga = (const int4*)(pah + k0);
      int4 a0 = ga[0], a1 = ga[1];
      sa[0] = a0; sa[1] = a1;
    }
    cvt16((const float4*)(pb + k0), sb);
    __syncthreads();
    bf16x8 af[4], bfv[4];
#pragma unroll
    for (int m = 0; m < 4; ++m)
      af[m] = *(const bf16x8*)(&As[(wr * 64 + m * 16 + fr) * 32 + fq * 8]);
#pragma unroll
    for (int n = 0; n < 4; ++n)
      bfv[n] = *(const bf16x8*)(&Bs[(wc * 64 + n * 16 + fr) * 32 + fq * 8]);
#pragma unroll
    for (int m = 0; m < 4; ++m)
#pragma unroll
      for (int n = 0; n < 4; ++n)
        acc[m][n] = __builtin_amdgcn_mfma_f32_16x16x32_bf16(af[m], bfv[n],
                                                            acc[m][n], 0, 0, 0);
    __syncthreads();
  }

#pragma unroll
  for (int m = 0; m < 4; ++m)
#pragma unroll
    for (int n = 0; n < 4; ++n)
#pragma unroll
      for (int r = 0; r < 4; ++r) {
        const int row = wr * 64 + m * 16 + fq * 4 + r;
        const int col = wc * 64 + n * 16 + fr;
        storeC(&C[(size_t)(m0 + row) * ldC + n0 + col], acc[m][n][r]);
      }
}

// ---------------------------------------------------------------------------
// RMSNorm + RoPE (unchanged — passing)
// ---------------------------------------------------------------------------
__global__ __launch_bounds__(256) void rms_rope(
    bf16_t* __restrict__ qkv, const float* __restrict__ cosb,
    const float* __restrict__ sinb, const float* __restrict__ qs,
    const float* __restrict__ ks)
{
  const int row = blockIdx.x;
  const int t = row & (T_SEQ - 1);
  const int tid = threadIdx.x;
  const int lane = tid & 63;
  const int wv = tid >> 6;
  const int f = lane & 15;
  const float c = (lane < 32) ? cosb[t * 16 + f] : 0.f;
  const float s = (lane < 32) ? sinb[t * 16 + f] : 0.f;
  for (int hh = wv; hh < 20; hh += 4) {
    const size_t idx = (size_t)row * LDQKV + hh * 64 + lane;
    const float v = __bfloat162float(qkv[idx]);
    float ssum = v * v;
#pragma unroll
    for (int off = 32; off; off >>= 1) ssum += __shfl_xor(ssum, off);
    const float norm = rsqrtf(ssum * (1.f / 64.f) + 1e-6f);
    const float scale = (hh < 16 ? qs : ks)[lane];
    float val = v * norm * scale;
    const float partner = __shfl_xor(val, 16);
    if (lane < 16)      val = val * c - partner * s;
    else if (lane < 32) val = partner * s + val * c;
    qkv[idx] = __float2bfloat16(val);
  }
}

// ---------------------------------------------------------------------------
// V transpose (unchanged — passing)
// ---------------------------------------------------------------------------
__global__ __launch_bounds__(256) void v_transpose(
    const bf16_t* __restrict__ qkv, bf16_t* __restrict__ v_t)
{
  __shared__ bf16_t tile[64 * 72];
  const int g = blockIdx.x;
  const int t0 = blockIdx.y * 64;
  const int tid = threadIdx.x;
  const int i = tid >> 2;
  const int dc = (tid & 3) * 16;
  const bf16_t* src = qkv + (size_t)((g >> 2) * T_SEQ + t0 + i) * LDQKV
                      + 1280 + (g & 3) * HD + dc;
  const int4* gs = (const int4*)src;
  int4 x0 = gs[0], x1 = gs[1];
  int4* st = (int4*)(&tile[i * 72 + dc]);
  st[0] = x0; st[1] = x1;
  __syncthreads();
  union { int4 v[2]; bf16_t h[16]; } u;
#pragma unroll
  for (int j = 0; j < 16; ++j) u.h[j] = tile[(dc + j) * 72 + i];
  int4* dst = (int4*)(v_t + (size_t)(g * HD + i) * T_SEQ + t0 + dc);
  dst[0] = u.v[0]; dst[1] = u.v[1];
}

// ---------------------------------------------------------------------------
// Causal GQA flash attention v3 — swapped-operand, barrier/LDS-free, plus:
// scale folded into Q (log2 domain), T13 defer-max (skip rescale unless row
// max grows >8), permlane32_swap P-fragment assembly, K-register prefetch.
// ---------------------------------------------------------------------------
__global__ __launch_bounds__(256) void attn(
    const bf16_t* __restrict__ qkv, const bf16_t* __restrict__ v_t,
    bf16_t* __restrict__ y)
{
  const int tid  = threadIdx.x;
  const int lane = tid & 63;
  const int wv   = tid >> 6;
  const int ql   = lane & 31;      // q within wave strip; also d_local for V
  const int hi   = lane >> 5;      // half-wave index
  const int bh   = blockIdx.x;
  const int b = bh >> 4, h = bh & 15, kvh = h >> 2;
  const int qb   = 15 - (int)blockIdx.y;   // longest first
  const int q0w  = qb * 128 + wv * 32;
  const int q_glob = q0w + ql;
  const float SCALE_LOG2 = 0.125f * 1.44269504089f;  // 1/sqrt(64) * log2(e)

  // Q fragments (B-operand), pre-scaled so QK^T lands in log2 domain
  const bf16_t* Qrow = qkv + (size_t)(b * T_SEQ + q_glob) * LDQKV + h * HD + hi * 8;
  bf16x8 qfrag[4];
#pragma unroll
  for (int c = 0; c < 4; ++c) {
    bf16x8 raw = *(const bf16x8*)(Qrow + c * 16);
    bf16x8 sc;
#pragma unroll
    for (int j = 0; j < 8; ++j)
      sc[j] = (__bf16)((float)raw[j] * SCALE_LOG2);
    qfrag[c] = sc;
  }

  // K base: lane's k-row = ql within tile
  const bf16_t* Kp = qkv + ((size_t)(b * T_SEQ + ql)) * LDQKV + 1024 + kvh * HD + hi * 8;
  // V base (v_t layout [g*64+d][t]): lane's d_local = ql
  const bf16_t* Vb = v_t + (size_t)((b * N_KV + kvh) * HD + ql) * T_SEQ + hi * 8;

#define LOADK4(dst, kk) { const bf16_t* _kp = Kp + (size_t)(kk) * LDQKV; \
    dst##0 = *(const bf16x8*)(_kp);      dst##1 = *(const bf16x8*)(_kp + 16); \
    dst##2 = *(const bf16x8*)(_kp + 32); dst##3 = *(const bf16x8*)(_kp + 48); }

  f32x16 acc0, acc1;
#pragma unroll
  for (int i = 0; i < 16; ++i) { acc0[i] = 0.f; acc1[i] = 0.f; }
  float m_run = -1e30f, l_run = 0.f;

  bf16x8 kc0, kc1, kc2, kc3;       // current K tile fragments
  bf16x8 kn0, kn1, kn2, kn3;       // prefetched next tile
  LOADK4(kc, 0);

  const int nb32 = (q0w >> 5) + 1;   // 32-k tiles; last is the masked diagonal
  for (int t = 0; t < nb32; ++t) {
    const int k0 = t << 5;
    const bool masked = (t == nb32 - 1);

    // V loads for this tile (consumed at the end -> latency covered)
    const bf16_t* Vp = Vb + k0;
    bf16x8 v0a = *(const bf16x8*)(Vp);
    bf16x8 v0b = *(const bf16x8*)(Vp + 16);
    bf16x8 v1a = *(const bf16x8*)(Vp + (size_t)32 * T_SEQ);
    bf16x8 v1b = *(const bf16x8*)(Vp + (size_t)32 * T_SEQ + 16);

    // QK^T (already log2-scaled via Q)
    f32x16 st;
#pragma unroll
    for (int i = 0; i < 16; ++i) st[i] = 0.f;
    st = __builtin_amdgcn_mfma_f32_32x32x16_bf16(kc0, qfrag[0], st, 0, 0, 0);
    st = __builtin_amdgcn_mfma_f32_32x32x16_bf16(kc1, qfrag[1], st, 0, 0, 0);
    st = __builtin_amdgcn_mfma_f32_32x32x16_bf16(kc2, qfrag[2], st, 0, 0, 0);
    st = __builtin_amdgcn_mfma_f32_32x32x16_bf16(kc3, qfrag[3], st, 0, 0, 0);

    // prefetch next K tile (hidden under softmax+PV below)
    if (t + 1 < nb32) { LOADK4(kn, k0 + 32); }

    // --- softmax, in-register, log2 domain ---
    float sreg[16];
#pragma unroll
    for (int r = 0; r < 16; ++r) sreg[r] = st[r];
    if (masked) {
#pragma unroll
      for (int r = 0; r < 16; ++r) {
        const int kg = k0 + (r & 3) + 8 * (r >> 2) + 4 * hi;
        if (kg > q_glob) sreg[r] = -1e30f;
      }
    }
    float bmax = fmaxf(fmaxf(fmaxf(sreg[0], sreg[1]), fmaxf(sreg[2], sreg[3])),
                       fmaxf(fmaxf(sreg[4], sreg[5]), fmaxf(sreg[6], sreg[7])));
    bmax = fmaxf(bmax,
           fmaxf(fmaxf(fmaxf(sreg[8], sreg[9]), fmaxf(sreg[10], sreg[11])),
                 fmaxf(fmaxf(sreg[12], sreg[13]), fmaxf(sreg[14], sreg[15]))));
    // T13 defer-max: only rescale when the row max grew materially (P <= 2^8)
    if (__any(bmax > m_run + 8.f)) {
      const float rmax = fmaxf(bmax, __shfl_xor(bmax, 32));
      const float mnew = fmaxf(m_run, rmax);
      const float corr = exp2f(m_run - mnew);
#pragma unroll
      for (int i = 0; i < 16; ++i) { acc0[i] *= corr; acc1[i] *= corr; }
      l_run *= corr;
      m_run = mnew;
    }
    float p[16];
    float lsum = 0.f;
#pragma unroll
    for (int r = 0; r < 16; ++r) { p[r] = exp2f(sreg[r] - m_run); lsum += p[r]; }
    lsum += __shfl_xor(lsum, 32);
    l_run += lsum;

    // --- pack P^T B-fragments via permlane32_swap ---
    // desired: f1 = { {w0_L,w2_L}, {w1_L,w3_L}, {w0_U,w2_U}, {w1_U,w3_U} }
    // plswap(a,b) -> a={a_L,b_L}, b={a_U,b_U}  => call with (low, high) order.
    union pk { __hip_bfloat162 h2; unsigned u; };
    unsigned w[8];
#pragma unroll
    for (int i = 0; i < 8; ++i) {
      pk t2; t2.h2 = __float22bfloat162_rn(make_float2(p[2 * i], p[2 * i + 1]));
      w[i] = t2.u;
    }
    plswap(w[0], w[2]); plswap(w[1], w[3]);
    plswap(w[4], w[6]); plswap(w[5], w[7]);
    union fu { unsigned u[4]; bf16x8 v; };
    fu f1, f2;
    f1.u[0] = w[0]; f1.u[1] = w[1]; f1.u[2] = w[2]; f1.u[3] = w[3];
    f2.u[0] = w[4]; f2.u[1] = w[5]; f2.u[2] = w[6]; f2.u[3] = w[7];

    // --- PV: O^T accumulate (A = V^T rows d, B = P^T) ---
    acc0 = __builtin_amdgcn_mfma_f32_32x32x16_bf16(v0a, f1.v, acc0, 0, 0, 0);
    acc0 = __builtin_amdgcn_mfma_f32_32x32x16_bf16(v0b, f2.v, acc0, 0, 0, 0);
    acc1 = __builtin_amdgcn_mfma_f32_32x32x16_bf16(v1a, f1.v, acc1, 0, 0, 0);
    acc1 = __builtin_amdgcn_mfma_f32_32x32x16_bf16(v1b, f2.v, acc1, 0, 0, 0);

    // rotate prefetched K into place (reg moves; waitcnt lands after PV)
    if (t + 1 < nb32) { kc0 = kn0; kc1 = kn1; kc2 = kn2; kc3 = kn3; }
  }

  // --- epilogue: O = acc / l_run ---
  const float inv = 1.f / l_run;
  bf16_t* yrow = y + (size_t)(b * T_SEQ + q_glob) * D_MODEL + h * HD;
  union st8 { uint2 u2; __hip_bfloat162 h2[2]; };
#pragma unroll
  for (int gg = 0; gg < 4; ++gg) {
    st8 o0, o1;
    o0.h2[0] = __float22bfloat162_rn(make_float2(acc0[4 * gg + 0] * inv, acc0[4 * gg + 1] * inv));
    o0.h2[1] = __float22bfloat162_rn(make_float2(acc0[4 * gg + 2] * inv, acc0[4 * gg + 3] * inv));
    o1.h2[0] = __float22bfloat162_rn(make_float2(acc1[4 * gg + 0] * inv, acc1[4 * gg + 1] * inv));
    o1.h2[1] = __float22bfloat162_rn(make_float2(acc1[4 * gg + 2] * inv, acc1[4 * gg + 3] * inv));
    *(uint2*)(yrow + 8 * gg + 4 * hi)      = o0.u2;
    *(uint2*)(yrow + 32 + 8 * gg + 4 * hi) = o1.u2;
  }
}

// ---------------------------------------------------------------------------
extern "C" void kernel_launch(void* const* d_in, const int* in_sizes, int n_in,
                              void* d_out, int out_size, void* d_ws,
                              size_t ws_size, hipStream_t stream) {
  const float* x    = (const float*)d_in[0];
  const float* cosb = (const float*)d_in[1];
  const float* sinb = (const float*)d_in[2];
  const float* Wq   = (const float*)d_in[3];
  const float* Wk   = (const float*)d_in[4];
  const float* Wv   = (const float*)d_in[5];
  const float* Wo   = (const float*)d_in[6];
  const float* qs   = (const float*)d_in[7];
  const float* ks   = (const float*)d_in[8];
  float* out = (float*)d_out;   // reference output dtype is float32

  char* ws = (char*)d_ws;
  bf16_t* qkv = (bf16_t*)ws;                                   // 25165824 B
  bf16_t* v_t = (bf16_t*)(ws + 25165824);                      // 4194304 B
  bf16_t* y   = (bf16_t*)(ws + 25165824 + 4194304);            // 16777216 B

  gemm_bt<true, bf16_t><<<dim3(12, 64), 256, 0, stream>>>(x, Wq, Wk, Wv, qkv, LDQKV);
  rms_rope<<<dim3(8192), 256, 0, stream>>>(qkv, cosb, sinb, qs, ks);
  v_transpose<<<dim3(16, 32), 256, 0, stream>>>(qkv, v_t);
  attn<<<dim3(64, 16), 256, 0, stream>>>(qkv, v_t, y);
  gemm_bt<false, float><<<dim3(8, 64), 256, 0, stream>>>(y, Wo, Wo, Wo, out, D_MODEL);
}

// Round 7
// 249.363 us; speedup vs baseline: 1.3066x; 1.0413x over previous
//
#include <hip/hip_runtime.h>
#include <hip/hip_bf16.h>
#include <stdint.h>

typedef __attribute__((ext_vector_type(8)))  __bf16 bf16x8;
typedef __attribute__((ext_vector_type(4)))  float  f32x4;
typedef __attribute__((ext_vector_type(16))) float  f32x16;
typedef __hip_bfloat16 bf16_t;

#define T_SEQ 2048
#define D_MODEL 1024
#define N_HEADS 16
#define N_KV 4
#define HD 64
#define LDQKV 1536
#define KDIM 1024

// Convert 16 consecutive fp32 (4x float4) -> 16 bf16 (2x int4)
__device__ inline void cvt16(const float4* __restrict__ g, int4* __restrict__ s) {
  float4 v0 = g[0], v1 = g[1], v2 = g[2], v3 = g[3];
  union { int4 i[2]; __hip_bfloat162 h[8]; } u;
  u.h[0] = __float22bfloat162_rn(make_float2(v0.x, v0.y));
  u.h[1] = __float22bfloat162_rn(make_float2(v0.z, v0.w));
  u.h[2] = __float22bfloat162_rn(make_float2(v1.x, v1.y));
  u.h[3] = __float22bfloat162_rn(make_float2(v1.z, v1.w));
  u.h[4] = __float22bfloat162_rn(make_float2(v2.x, v2.y));
  u.h[5] = __float22bfloat162_rn(make_float2(v2.z, v2.w));
  u.h[6] = __float22bfloat162_rn(make_float2(v3.x, v3.y));
  u.h[7] = __float22bfloat162_rn(make_float2(v3.z, v3.w));
  s[0] = u.i[0]; s[1] = u.i[1];
}

__device__ inline void storeC(bf16_t* p, float v) { *p = __float2bfloat16(v); }
__device__ inline void storeC(float* p, float v) { *p = v; }

// v_permlane32_swap_b32 vdst, vsrc: after plswap(a,b): a={a_L,b_L}, b={a_U,b_U}
__device__ inline void plswap(unsigned& a, unsigned& b) {
  asm volatile("v_permlane32_swap_b32 %0, %1" : "+v"(a), "+v"(b));
}

// ---------------------------------------------------------------------------
// GEMM (unchanged — passing)
// ---------------------------------------------------------------------------
template <bool A_F32, typename CT>
__global__ __launch_bounds__(256) void gemm_bt(
    const void* __restrict__ Ap,
    const float* __restrict__ W0, const float* __restrict__ W1,
    const float* __restrict__ W2,
    CT* __restrict__ C, const int ldC)
{
  __shared__ bf16_t As[128 * 32];
  __shared__ bf16_t Bs[128 * 32];
  const int tid = threadIdx.x;
  const int lane = tid & 63;
  const int wv = tid >> 6;
  const int wr = wv >> 1, wc = wv & 1;
  const int m0 = blockIdx.y * 128;
  const int n0 = blockIdx.x * 128;
  const float* W = W0; int nr0 = n0;
  if (n0 >= 1280)      { W = W2; nr0 = n0 - 1280; }
  else if (n0 >= 1024) { W = W1; nr0 = n0 - 1024; }

  const int ra = tid >> 1;
  const int ca = (tid & 1) * 16;
  const float*  paf = (const float*)Ap  + (size_t)(m0 + ra) * KDIM + ca;
  const bf16_t* pah = (const bf16_t*)Ap + (size_t)(m0 + ra) * KDIM + ca;
  const float*  pb  = W + (size_t)(nr0 + ra) * KDIM + ca;
  int4* sa = (int4*)(&As[ra * 32 + ca]);
  int4* sb = (int4*)(&Bs[ra * 32 + ca]);

  f32x4 acc[4][4];
#pragma unroll
  for (int m = 0; m < 4; ++m)
#pragma unroll
    for (int n = 0; n < 4; ++n)
      acc[m][n] = {0.f, 0.f, 0.f, 0.f};

  const int fr = lane & 15;
  const int fq = lane >> 4;

  for (int k0 = 0; k0 < KDIM; k0 += 32) {
    if constexpr (A_F32) {
      cvt16((const float4*)(paf + k0), sa);
    } else {
      const int4* ga = (const int4*)(pah + k0);
      int4 a0 = ga[0], a1 = ga[1];
      sa[0] = a0; sa[1] = a1;
    }
    cvt16((const float4*)(pb + k0), sb);
    __syncthreads();
    bf16x8 af[4], bfv[4];
#pragma unroll
    for (int m = 0; m < 4; ++m)
      af[m] = *(const bf16x8*)(&As[(wr * 64 + m * 16 + fr) * 32 + fq * 8]);
#pragma unroll
    for (int n = 0; n < 4; ++n)
      bfv[n] = *(const bf16x8*)(&Bs[(wc * 64 + n * 16 + fr) * 32 + fq * 8]);
#pragma unroll
    for (int m = 0; m < 4; ++m)
#pragma unroll
      for (int n = 0; n < 4; ++n)
        acc[m][n] = __builtin_amdgcn_mfma_f32_16x16x32_bf16(af[m], bfv[n],
                                                            acc[m][n], 0, 0, 0);
    __syncthreads();
  }

#pragma unroll
  for (int m = 0; m < 4; ++m)
#pragma unroll
    for (int n = 0; n < 4; ++n)
#pragma unroll
      for (int r = 0; r < 4; ++r) {
        const int row = wr * 64 + m * 16 + fq * 4 + r;
        const int col = wc * 64 + n * 16 + fr;
        storeC(&C[(size_t)(m0 + row) * ldC + n0 + col], acc[m][n][r]);
      }
}

// ---------------------------------------------------------------------------
// RMSNorm + RoPE (unchanged — passing)
// ---------------------------------------------------------------------------
__global__ __launch_bounds__(256) void rms_rope(
    bf16_t* __restrict__ qkv, const float* __restrict__ cosb,
    const float* __restrict__ sinb, const float* __restrict__ qs,
    const float* __restrict__ ks)
{
  const int row = blockIdx.x;
  const int t = row & (T_SEQ - 1);
  const int tid = threadIdx.x;
  const int lane = tid & 63;
  const int wv = tid >> 6;
  const int f = lane & 15;
  const float c = (lane < 32) ? cosb[t * 16 + f] : 0.f;
  const float s = (lane < 32) ? sinb[t * 16 + f] : 0.f;
  for (int hh = wv; hh < 20; hh += 4) {
    const size_t idx = (size_t)row * LDQKV + hh * 64 + lane;
    const float v = __bfloat162float(qkv[idx]);
    float ssum = v * v;
#pragma unroll
    for (int off = 32; off; off >>= 1) ssum += __shfl_xor(ssum, off);
    const float norm = rsqrtf(ssum * (1.f / 64.f) + 1e-6f);
    const float scale = (hh < 16 ? qs : ks)[lane];
    float val = v * norm * scale;
    const float partner = __shfl_xor(val, 16);
    if (lane < 16)      val = val * c - partner * s;
    else if (lane < 32) val = partner * s + val * c;
    qkv[idx] = __float2bfloat16(val);
  }
}

// ---------------------------------------------------------------------------
// V transpose (unchanged — passing)
// ---------------------------------------------------------------------------
__global__ __launch_bounds__(256) void v_transpose(
    const bf16_t* __restrict__ qkv, bf16_t* __restrict__ v_t)
{
  __shared__ bf16_t tile[64 * 72];
  const int g = blockIdx.x;
  const int t0 = blockIdx.y * 64;
  const int tid = threadIdx.x;
  const int i = tid >> 2;
  const int dc = (tid & 3) * 16;
  const bf16_t* src = qkv + (size_t)((g >> 2) * T_SEQ + t0 + i) * LDQKV
                      + 1280 + (g & 3) * HD + dc;
  const int4* gs = (const int4*)src;
  int4 x0 = gs[0], x1 = gs[1];
  int4* st = (int4*)(&tile[i * 72 + dc]);
  st[0] = x0; st[1] = x1;
  __syncthreads();
  union { int4 v[2]; bf16_t h[16]; } u;
#pragma unroll
  for (int j = 0; j < 16; ++j) u.h[j] = tile[(dc + j) * 72 + i];
  int4* dst = (int4*)(v_t + (size_t)(g * HD + i) * T_SEQ + t0 + dc);
  dst[0] = u.v[0]; dst[1] = u.v[1];
}

// ---------------------------------------------------------------------------
// Causal GQA flash attention v4 — swapped-operand, barrier/LDS-free.
// NEW: uniform work (wave processes strip s and strip 63-s => exactly 65
// tiles/wave), V prefetch alongside K, XCD-clustered block decode so the 32
// blocks sharing one (b,kvh) K/V pair carry the same id%8.
// ---------------------------------------------------------------------------
__global__ __launch_bounds__(256) void attn(
    const bf16_t* __restrict__ qkv, const bf16_t* __restrict__ v_t,
    bf16_t* __restrict__ y)
{
  const int tid  = threadIdx.x;
  const int lane = tid & 63;
  const int wv   = tid >> 6;
  const int ql   = lane & 31;      // q within strip; also d_local for V
  const int hi   = lane >> 5;      // half-wave index
  // XCD-clustered decode: id%8 + 8*gsel = b*4+kvh, so same-(b,kvh) blocks
  // share id%8 (-> same XCD under round-robin dispatch).
  const int id   = (int)blockIdx.x;          // 0..511
  const int low3 = id & 7;
  const int r    = id >> 3;                  // 0..63
  const int gsel = r & 1;
  const int hh   = (r >> 1) & 3;
  const int p    = r >> 3;                   // 0..7
  const int g16  = low3 + 8 * gsel;          // b*4+kvh
  const int b    = g16 >> 2, kvh = g16 & 3;
  const int h    = kvh * 4 + hh;
  const int sA   = p * 4 + wv;               // 0..31; pair with 63-sA
  const float SCALE_LOG2 = 0.125f * 1.44269504089f;  // 1/sqrt(64)*log2(e)

  // strip-independent K/V bases (lane's k-row / d-row = ql)
  const bf16_t* Kp = qkv + ((size_t)(b * T_SEQ + ql)) * LDQKV + 1024 + kvh * HD + hi * 8;
  const bf16_t* Vb = v_t + (size_t)((b * N_KV + kvh) * HD + ql) * T_SEQ + hi * 8;

#define LOADK4(dst, kk) { const bf16_t* _kp = Kp + (size_t)(kk) * LDQKV; \
    dst##0 = *(const bf16x8*)(_kp);      dst##1 = *(const bf16x8*)(_kp + 16); \
    dst##2 = *(const bf16x8*)(_kp + 32); dst##3 = *(const bf16x8*)(_kp + 48); }
#define LOADV4(dst, kk) { const bf16_t* _vp = Vb + (kk); \
    dst##0 = *(const bf16x8*)(_vp);      dst##1 = *(const bf16x8*)(_vp + 16); \
    dst##2 = *(const bf16x8*)(_vp + (size_t)32 * T_SEQ); \
    dst##3 = *(const bf16x8*)(_vp + (size_t)32 * T_SEQ + 16); }

#pragma unroll
  for (int pi = 0; pi < 2; ++pi) {
    const int s = pi ? (63 - sA) : sA;
    const int q_glob = s * 32 + ql;
    const int nt = s + 1;                    // tiles; last is masked diagonal

    // Q fragments (B-operand), pre-scaled into log2 domain
    const bf16_t* Qrow = qkv + (size_t)(b * T_SEQ + q_glob) * LDQKV + h * HD + hi * 8;
    bf16x8 qfrag[4];
#pragma unroll
    for (int c = 0; c < 4; ++c) {
      bf16x8 raw = *(const bf16x8*)(Qrow + c * 16);
      bf16x8 sc;
#pragma unroll
      for (int j = 0; j < 8; ++j)
        sc[j] = (__bf16)((float)raw[j] * SCALE_LOG2);
      qfrag[c] = sc;
    }

    f32x16 acc0, acc1;
#pragma unroll
    for (int i = 0; i < 16; ++i) { acc0[i] = 0.f; acc1[i] = 0.f; }
    float m_run = -1e30f, l_run = 0.f;

    bf16x8 kc0, kc1, kc2, kc3, kn0, kn1, kn2, kn3;
    bf16x8 vc0, vc1, vc2, vc3, vn0, vn1, vn2, vn3;
    LOADK4(kc, 0);
    LOADV4(vc, 0);

    for (int t = 0; t < nt; ++t) {
      const int k0 = t << 5;
      const bool masked = (t == nt - 1);

      // QK^T (log2-scaled via Q)
      f32x16 st;
#pragma unroll
      for (int i = 0; i < 16; ++i) st[i] = 0.f;
      st = __builtin_amdgcn_mfma_f32_32x32x16_bf16(kc0, qfrag[0], st, 0, 0, 0);
      st = __builtin_amdgcn_mfma_f32_32x32x16_bf16(kc1, qfrag[1], st, 0, 0, 0);
      st = __builtin_amdgcn_mfma_f32_32x32x16_bf16(kc2, qfrag[2], st, 0, 0, 0);
      st = __builtin_amdgcn_mfma_f32_32x32x16_bf16(kc3, qfrag[3], st, 0, 0, 0);

      // prefetch next tile's K AND V (hidden under softmax+PV)
      if (t + 1 < nt) { LOADK4(kn, k0 + 32); LOADV4(vn, k0 + 32); }

      // softmax, in-register, log2 domain
      float sreg[16];
#pragma unroll
      for (int rr = 0; rr < 16; ++rr) sreg[rr] = st[rr];
      if (masked) {
#pragma unroll
        for (int rr = 0; rr < 16; ++rr) {
          const int kg = k0 + (rr & 3) + 8 * (rr >> 2) + 4 * hi;
          if (kg > q_glob) sreg[rr] = -1e30f;
        }
      }
      float bmax = fmaxf(fmaxf(fmaxf(sreg[0], sreg[1]), fmaxf(sreg[2], sreg[3])),
                         fmaxf(fmaxf(sreg[4], sreg[5]), fmaxf(sreg[6], sreg[7])));
      bmax = fmaxf(bmax,
             fmaxf(fmaxf(fmaxf(sreg[8], sreg[9]), fmaxf(sreg[10], sreg[11])),
                   fmaxf(fmaxf(sreg[12], sreg[13]), fmaxf(sreg[14], sreg[15]))));
      // T13 defer-max: rescale only when the row max grows >8 (P <= 2^8)
      if (__any(bmax > m_run + 8.f)) {
        const float rmax = fmaxf(bmax, __shfl_xor(bmax, 32));
        const float mnew = fmaxf(m_run, rmax);
        const float corr = exp2f(m_run - mnew);
#pragma unroll
        for (int i = 0; i < 16; ++i) { acc0[i] *= corr; acc1[i] *= corr; }
        l_run *= corr;
        m_run = mnew;
      }
      float pp[16];
      float lsum = 0.f;
#pragma unroll
      for (int rr = 0; rr < 16; ++rr) { pp[rr] = exp2f(sreg[rr] - m_run); lsum += pp[rr]; }
      lsum += __shfl_xor(lsum, 32);
      l_run += lsum;

      // pack P^T B-fragments via permlane32_swap
      union pk { __hip_bfloat162 h2; unsigned u; };
      unsigned w[8];
#pragma unroll
      for (int i = 0; i < 8; ++i) {
        pk t2; t2.h2 = __float22bfloat162_rn(make_float2(pp[2 * i], pp[2 * i + 1]));
        w[i] = t2.u;
      }
      plswap(w[0], w[2]); plswap(w[1], w[3]);
      plswap(w[4], w[6]); plswap(w[5], w[7]);
      union fu { unsigned u[4]; bf16x8 v; };
      fu f1, f2;
      f1.u[0] = w[0]; f1.u[1] = w[1]; f1.u[2] = w[2]; f1.u[3] = w[3];
      f2.u[0] = w[4]; f2.u[1] = w[5]; f2.u[2] = w[6]; f2.u[3] = w[7];

      // PV: O^T accumulate (A = V^T rows d, B = P^T)
      acc0 = __builtin_amdgcn_mfma_f32_32x32x16_bf16(vc0, f1.v, acc0, 0, 0, 0);
      acc0 = __builtin_amdgcn_mfma_f32_32x32x16_bf16(vc1, f2.v, acc0, 0, 0, 0);
      acc1 = __builtin_amdgcn_mfma_f32_32x32x16_bf16(vc2, f1.v, acc1, 0, 0, 0);
      acc1 = __builtin_amdgcn_mfma_f32_32x32x16_bf16(vc3, f2.v, acc1, 0, 0, 0);

      // rotate prefetched tiles into place
      if (t + 1 < nt) {
        kc0 = kn0; kc1 = kn1; kc2 = kn2; kc3 = kn3;
        vc0 = vn0; vc1 = vn1; vc2 = vn2; vc3 = vn3;
      }
    }

    // epilogue: O = acc / l_run
    const float inv = 1.f / l_run;
    bf16_t* yrow = y + (size_t)(b * T_SEQ + q_glob) * D_MODEL + h * HD;
    union st8 { uint2 u2; __hip_bfloat162 h2[2]; };
#pragma unroll
    for (int gg = 0; gg < 4; ++gg) {
      st8 o0, o1;
      o0.h2[0] = __float22bfloat162_rn(make_float2(acc0[4 * gg + 0] * inv, acc0[4 * gg + 1] * inv));
      o0.h2[1] = __float22bfloat162_rn(make_float2(acc0[4 * gg + 2] * inv, acc0[4 * gg + 3] * inv));
      o1.h2[0] = __float22bfloat162_rn(make_float2(acc1[4 * gg + 0] * inv, acc1[4 * gg + 1] * inv));
      o1.h2[1] = __float22bfloat162_rn(make_float2(acc1[4 * gg + 2] * inv, acc1[4 * gg + 3] * inv));
      *(uint2*)(yrow + 8 * gg + 4 * hi)      = o0.u2;
      *(uint2*)(yrow + 32 + 8 * gg + 4 * hi) = o1.u2;
    }
  }
#undef LOADK4
#undef LOADV4
}

// ---------------------------------------------------------------------------
extern "C" void kernel_launch(void* const* d_in, const int* in_sizes, int n_in,
                              void* d_out, int out_size, void* d_ws,
                              size_t ws_size, hipStream_t stream) {
  const float* x    = (const float*)d_in[0];
  const float* cosb = (const float*)d_in[1];
  const float* sinb = (const float*)d_in[2];
  const float* Wq   = (const float*)d_in[3];
  const float* Wk   = (const float*)d_in[4];
  const float* Wv   = (const float*)d_in[5];
  const float* Wo   = (const float*)d_in[6];
  const float* qs   = (const float*)d_in[7];
  const float* ks   = (const float*)d_in[8];
  float* out = (float*)d_out;   // reference output dtype is float32

  char* ws = (char*)d_ws;
  bf16_t* qkv = (bf16_t*)ws;                                   // 25165824 B
  bf16_t* v_t = (bf16_t*)(ws + 25165824);                      // 4194304 B
  bf16_t* y   = (bf16_t*)(ws + 25165824 + 4194304);            // 16777216 B

  gemm_bt<true, bf16_t><<<dim3(12, 64), 256, 0, stream>>>(x, Wq, Wk, Wv, qkv, LDQKV);
  rms_rope<<<dim3(8192), 256, 0, stream>>>(qkv, cosb, sinb, qs, ks);
  v_transpose<<<dim3(16, 32), 256, 0, stream>>>(qkv, v_t);
  attn<<<dim3(512), 256, 0, stream>>>(qkv, v_t, y);
  gemm_bt<false, float><<<dim3(8, 64), 256, 0, stream>>>(y, Wo, Wo, Wo, out, D_MODEL);
}

// Round 8
// 233.943 us; speedup vs baseline: 1.3928x; 1.0659x over previous
//
#include <hip/hip_runtime.h>
#include <hip/hip_bf16.h>
#include <stdint.h>

typedef __attribute__((ext_vector_type(8)))  __bf16 bf16x8;
typedef __attribute__((ext_vector_type(4)))  float  f32x4;
typedef __attribute__((ext_vector_type(16))) float  f32x16;
typedef __hip_bfloat16 bf16_t;

#define T_SEQ 2048
#define D_MODEL 1024
#define N_HEADS 16
#define N_KV 4
#define HD 64
#define LDQKV 1536
#define KDIM 1024

// Convert 16 consecutive fp32 (4x float4) -> 16 bf16 (2x int4)
__device__ inline void cvt16(const float4* __restrict__ g, int4* __restrict__ s) {
  float4 v0 = g[0], v1 = g[1], v2 = g[2], v3 = g[3];
  union { int4 i[2]; __hip_bfloat162 h[8]; } u;
  u.h[0] = __float22bfloat162_rn(make_float2(v0.x, v0.y));
  u.h[1] = __float22bfloat162_rn(make_float2(v0.z, v0.w));
  u.h[2] = __float22bfloat162_rn(make_float2(v1.x, v1.y));
  u.h[3] = __float22bfloat162_rn(make_float2(v1.z, v1.w));
  u.h[4] = __float22bfloat162_rn(make_float2(v2.x, v2.y));
  u.h[5] = __float22bfloat162_rn(make_float2(v2.z, v2.w));
  u.h[6] = __float22bfloat162_rn(make_float2(v3.x, v3.y));
  u.h[7] = __float22bfloat162_rn(make_float2(v3.z, v3.w));
  s[0] = u.i[0]; s[1] = u.i[1];
}

__device__ inline void storeC(bf16_t* p, float v) { *p = __float2bfloat16(v); }
__device__ inline void storeC(float* p, float v) { *p = v; }

// v_permlane32_swap_b32 vdst, vsrc: after plswap(a,b): a={a_L,b_L}, b={a_U,b_U}
__device__ inline void plswap(unsigned& a, unsigned& b) {
  asm volatile("v_permlane32_swap_b32 %0, %1" : "+v"(a), "+v"(b));
}

// ---------------------------------------------------------------------------
// GEMM (unchanged — passing)
// ---------------------------------------------------------------------------
template <bool A_F32, typename CT>
__global__ __launch_bounds__(256) void gemm_bt(
    const void* __restrict__ Ap,
    const float* __restrict__ W0, const float* __restrict__ W1,
    const float* __restrict__ W2,
    CT* __restrict__ C, const int ldC)
{
  __shared__ bf16_t As[128 * 32];
  __shared__ bf16_t Bs[128 * 32];
  const int tid = threadIdx.x;
  const int lane = tid & 63;
  const int wv = tid >> 6;
  const int wr = wv >> 1, wc = wv & 1;
  const int m0 = blockIdx.y * 128;
  const int n0 = blockIdx.x * 128;
  const float* W = W0; int nr0 = n0;
  if (n0 >= 1280)      { W = W2; nr0 = n0 - 1280; }
  else if (n0 >= 1024) { W = W1; nr0 = n0 - 1024; }

  const int ra = tid >> 1;
  const int ca = (tid & 1) * 16;
  const float*  paf = (const float*)Ap  + (size_t)(m0 + ra) * KDIM + ca;
  const bf16_t* pah = (const bf16_t*)Ap + (size_t)(m0 + ra) * KDIM + ca;
  const float*  pb  = W + (size_t)(nr0 + ra) * KDIM + ca;
  int4* sa = (int4*)(&As[ra * 32 + ca]);
  int4* sb = (int4*)(&Bs[ra * 32 + ca]);

  f32x4 acc[4][4];
#pragma unroll
  for (int m = 0; m < 4; ++m)
#pragma unroll
    for (int n = 0; n < 4; ++n)
      acc[m][n] = {0.f, 0.f, 0.f, 0.f};

  const int fr = lane & 15;
  const int fq = lane >> 4;

  for (int k0 = 0; k0 < KDIM; k0 += 32) {
    if constexpr (A_F32) {
      cvt16((const float4*)(paf + k0), sa);
    } else {
      const int4* ga = (const int4*)(pah + k0);
      int4 a0 = ga[0], a1 = ga[1];
      sa[0] = a0; sa[1] = a1;
    }
    cvt16((const float4*)(pb + k0), sb);
    __syncthreads();
    bf16x8 af[4], bfv[4];
#pragma unroll
    for (int m = 0; m < 4; ++m)
      af[m] = *(const bf16x8*)(&As[(wr * 64 + m * 16 + fr) * 32 + fq * 8]);
#pragma unroll
    for (int n = 0; n < 4; ++n)
      bfv[n] = *(const bf16x8*)(&Bs[(wc * 64 + n * 16 + fr) * 32 + fq * 8]);
#pragma unroll
    for (int m = 0; m < 4; ++m)
#pragma unroll
      for (int n = 0; n < 4; ++n)
        acc[m][n] = __builtin_amdgcn_mfma_f32_16x16x32_bf16(af[m], bfv[n],
                                                            acc[m][n], 0, 0, 0);
    __syncthreads();
  }

#pragma unroll
  for (int m = 0; m < 4; ++m)
#pragma unroll
    for (int n = 0; n < 4; ++n)
#pragma unroll
      for (int r = 0; r < 4; ++r) {
        const int row = wr * 64 + m * 16 + fq * 4 + r;
        const int col = wc * 64 + n * 16 + fr;
        storeC(&C[(size_t)(m0 + row) * ldC + n0 + col], acc[m][n][r]);
      }
}

// ---------------------------------------------------------------------------
// RMSNorm + RoPE (unchanged — passing)
// ---------------------------------------------------------------------------
__global__ __launch_bounds__(256) void rms_rope(
    bf16_t* __restrict__ qkv, const float* __restrict__ cosb,
    const float* __restrict__ sinb, const float* __restrict__ qs,
    const float* __restrict__ ks)
{
  const int row = blockIdx.x;
  const int t = row & (T_SEQ - 1);
  const int tid = threadIdx.x;
  const int lane = tid & 63;
  const int wv = tid >> 6;
  const int f = lane & 15;
  const float c = (lane < 32) ? cosb[t * 16 + f] : 0.f;
  const float s = (lane < 32) ? sinb[t * 16 + f] : 0.f;
  for (int hh = wv; hh < 20; hh += 4) {
    const size_t idx = (size_t)row * LDQKV + hh * 64 + lane;
    const float v = __bfloat162float(qkv[idx]);
    float ssum = v * v;
#pragma unroll
    for (int off = 32; off; off >>= 1) ssum += __shfl_xor(ssum, off);
    const float norm = rsqrtf(ssum * (1.f / 64.f) + 1e-6f);
    const float scale = (hh < 16 ? qs : ks)[lane];
    float val = v * norm * scale;
    const float partner = __shfl_xor(val, 16);
    if (lane < 16)      val = val * c - partner * s;
    else if (lane < 32) val = partner * s + val * c;
    qkv[idx] = __float2bfloat16(val);
  }
}

// ---------------------------------------------------------------------------
// V transpose (unchanged — passing)
// ---------------------------------------------------------------------------
__global__ __launch_bounds__(256) void v_transpose(
    const bf16_t* __restrict__ qkv, bf16_t* __restrict__ v_t)
{
  __shared__ bf16_t tile[64 * 72];
  const int g = blockIdx.x;
  const int t0 = blockIdx.y * 64;
  const int tid = threadIdx.x;
  const int i = tid >> 2;
  const int dc = (tid & 3) * 16;
  const bf16_t* src = qkv + (size_t)((g >> 2) * T_SEQ + t0 + i) * LDQKV
                      + 1280 + (g & 3) * HD + dc;
  const int4* gs = (const int4*)src;
  int4 x0 = gs[0], x1 = gs[1];
  int4* st = (int4*)(&tile[i * 72 + dc]);
  st[0] = x0; st[1] = x1;
  __syncthreads();
  union { int4 v[2]; bf16_t h[16]; } u;
#pragma unroll
  for (int j = 0; j < 16; ++j) u.h[j] = tile[(dc + j) * 72 + i];
  int4* dst = (int4*)(v_t + (size_t)(g * HD + i) * T_SEQ + t0 + dc);
  dst[0] = u.v[0]; dst[1] = u.v[1];
}

// ---------------------------------------------------------------------------
// Causal GQA flash attention v5 — swapped-operand, in-register softmax, plus
// cooperative LDS staging of K/V tiles (coalesced global loads, XOR-swizzled
// LDS, double-buffered, reg-staged issue-early/write-late). 4 waves share one
// (b,kvh) K/V stream; wave handles strip s=4p+wv (pass0) and 63-s (pass1).
// LDS map (int4 units): K tile buf b at [b*256 + k*8 + slot], slot=(d16)^(k&7)
//                       V tile buf b at [512 + b*256 + d*4 + slot], slot=(t16)^(d&3)
// ---------------------------------------------------------------------------
__global__ __launch_bounds__(256) void attn(
    const bf16_t* __restrict__ qkv, const bf16_t* __restrict__ v_t,
    bf16_t* __restrict__ y)
{
  __shared__ int4 lds[1024];      // 16 KB: K dbuf 2x4KB | V dbuf 2x4KB
  const int tid  = threadIdx.x;
  const int lane = tid & 63;
  const int wv   = tid >> 6;
  const int ql   = lane & 31;      // q within strip; also d_local for V frags
  const int hi   = lane >> 5;      // half-wave index
  // XCD-clustered decode: same-(b,kvh) blocks share id%8.
  const int id   = (int)blockIdx.x;          // 0..511
  const int low3 = id & 7;
  const int r    = id >> 3;                  // 0..63
  const int gsel = r & 1;
  const int hh   = (r >> 1) & 3;
  const int p    = r >> 3;                   // 0..7
  const int g16  = low3 + 8 * gsel;          // b*4+kvh
  const int b    = g16 >> 2, kvh = g16 & 3;
  const int h    = kvh * 4 + hh;
  const int sA   = p * 4 + wv;               // 0..31; pair with 63-sA
  const float SCALE_LOG2 = 0.125f * 1.44269504089f;  // 1/sqrt(64)*log2(e)

  // --- per-thread staging addresses (tile-relative) ---
  const int kr = tid >> 3, kslot = tid & 7;          // K: row 0..31, 16B slot
  const int vd = tid >> 2, vslot = tid & 3;          // V: d-row 0..63, slot
  const bf16_t* gK = qkv + (size_t)(b * T_SEQ + kr) * LDQKV + 1024 + kvh * HD + kslot * 8;
  const bf16_t* gV = v_t + (size_t)((b * N_KV + kvh) * HD + vd) * T_SEQ + vslot * 8;
  const int wKidx = kr * 8 + (kslot ^ (kr & 7));            // swizzled write slot
  const int wVidx = 512 + vd * 4 + (vslot ^ (vd & 3));

  // --- per-lane fragment read indices (tile-relative, int4 units) ---
  int kridx[4];
#pragma unroll
  for (int c = 0; c < 4; ++c)
    kridx[c] = ql * 8 + ((2 * c + hi) ^ (ql & 7));
  const int v0idx = 512 + ql * 4 + (hi ^ (ql & 3));
  const int v1idx = 512 + ql * 4 + ((2 + hi) ^ (ql & 3));
  const int v2idx = 512 + (ql + 32) * 4 + (hi ^ (ql & 3));
  const int v3idx = 512 + (ql + 32) * 4 + ((2 + hi) ^ (ql & 3));

#pragma unroll
  for (int pi = 0; pi < 2; ++pi) {
    const int s = pi ? (63 - sA) : sA;
    const int q_glob = s * 32 + ql;
    const int nt = s + 1;                         // this wave's tiles
    const int ntmax = pi ? (64 - 4 * p) : (4 * p + 4);   // block-uniform

    // Q fragments (B-operand), pre-scaled into log2 domain
    const bf16_t* Qrow = qkv + (size_t)(b * T_SEQ + q_glob) * LDQKV + h * HD + hi * 8;
    bf16x8 qfrag[4];
#pragma unroll
    for (int c = 0; c < 4; ++c) {
      bf16x8 raw = *(const bf16x8*)(Qrow + c * 16);
      bf16x8 sc;
#pragma unroll
      for (int j = 0; j < 8; ++j)
        sc[j] = (__bf16)((float)raw[j] * SCALE_LOG2);
      qfrag[c] = sc;
    }

    f32x16 acc0, acc1;
#pragma unroll
    for (int i = 0; i < 16; ++i) { acc0[i] = 0.f; acc1[i] = 0.f; }
    float m_run = -1e30f, l_run = 0.f;

    // prologue: stage tile 0 into buf 0
    {
      int4 kreg = *(const int4*)gK;
      int4 vreg = *(const int4*)gV;
      lds[wKidx] = kreg;
      lds[wVidx] = vreg;
    }
    __syncthreads();

    int buf = 0;
    for (int t = 0; t < ntmax; ++t) {
      // issue next tile's staging loads early (latency hides under compute)
      int4 kreg, vreg;
      const bool more = (t + 1 < ntmax);
      if (more) {
        kreg = *(const int4*)(gK + (size_t)(t + 1) * 32 * LDQKV);
        vreg = *(const int4*)(gV + (t + 1) * 32);
      }

      if (t < nt) {
        const int k0 = t << 5;
        const bool masked = (t == nt - 1);
        const int base = buf * 256;

        bf16x8 kf0 = *(const bf16x8*)&lds[base + kridx[0]];
        bf16x8 kf1 = *(const bf16x8*)&lds[base + kridx[1]];
        bf16x8 kf2 = *(const bf16x8*)&lds[base + kridx[2]];
        bf16x8 kf3 = *(const bf16x8*)&lds[base + kridx[3]];

        f32x16 st;
#pragma unroll
        for (int i = 0; i < 16; ++i) st[i] = 0.f;
        st = __builtin_amdgcn_mfma_f32_32x32x16_bf16(kf0, qfrag[0], st, 0, 0, 0);
        st = __builtin_amdgcn_mfma_f32_32x32x16_bf16(kf1, qfrag[1], st, 0, 0, 0);
        st = __builtin_amdgcn_mfma_f32_32x32x16_bf16(kf2, qfrag[2], st, 0, 0, 0);
        st = __builtin_amdgcn_mfma_f32_32x32x16_bf16(kf3, qfrag[3], st, 0, 0, 0);

        // softmax, in-register, log2 domain
        float sreg[16];
#pragma unroll
        for (int rr = 0; rr < 16; ++rr) sreg[rr] = st[rr];
        if (masked) {
#pragma unroll
          for (int rr = 0; rr < 16; ++rr) {
            const int kg = k0 + (rr & 3) + 8 * (rr >> 2) + 4 * hi;
            if (kg > q_glob) sreg[rr] = -1e30f;
          }
        }
        float bmax = fmaxf(fmaxf(fmaxf(sreg[0], sreg[1]), fmaxf(sreg[2], sreg[3])),
                           fmaxf(fmaxf(sreg[4], sreg[5]), fmaxf(sreg[6], sreg[7])));
        bmax = fmaxf(bmax,
               fmaxf(fmaxf(fmaxf(sreg[8], sreg[9]), fmaxf(sreg[10], sreg[11])),
                     fmaxf(fmaxf(sreg[12], sreg[13]), fmaxf(sreg[14], sreg[15]))));
        if (__any(bmax > m_run + 8.f)) {        // T13 defer-max
          const float rmax = fmaxf(bmax, __shfl_xor(bmax, 32));
          const float mnew = fmaxf(m_run, rmax);
          const float corr = exp2f(m_run - mnew);
#pragma unroll
          for (int i = 0; i < 16; ++i) { acc0[i] *= corr; acc1[i] *= corr; }
          l_run *= corr;
          m_run = mnew;
        }
        float pp[16];
        float lsum = 0.f;
#pragma unroll
        for (int rr = 0; rr < 16; ++rr) { pp[rr] = exp2f(sreg[rr] - m_run); lsum += pp[rr]; }
        lsum += __shfl_xor(lsum, 32);
        l_run += lsum;

        // pack P^T B-fragments via permlane32_swap
        union pk { __hip_bfloat162 h2; unsigned u; };
        unsigned w[8];
#pragma unroll
        for (int i = 0; i < 8; ++i) {
          pk t2; t2.h2 = __float22bfloat162_rn(make_float2(pp[2 * i], pp[2 * i + 1]));
          w[i] = t2.u;
        }
        plswap(w[0], w[2]); plswap(w[1], w[3]);
        plswap(w[4], w[6]); plswap(w[5], w[7]);
        union fu { unsigned u[4]; bf16x8 v; };
        fu f1, f2;
        f1.u[0] = w[0]; f1.u[1] = w[1]; f1.u[2] = w[2]; f1.u[3] = w[3];
        f2.u[0] = w[4]; f2.u[1] = w[5]; f2.u[2] = w[6]; f2.u[3] = w[7];

        bf16x8 vf0 = *(const bf16x8*)&lds[base + v0idx];
        bf16x8 vf1 = *(const bf16x8*)&lds[base + v1idx];
        bf16x8 vf2 = *(const bf16x8*)&lds[base + v2idx];
        bf16x8 vf3 = *(const bf16x8*)&lds[base + v3idx];

        acc0 = __builtin_amdgcn_mfma_f32_32x32x16_bf16(vf0, f1.v, acc0, 0, 0, 0);
        acc0 = __builtin_amdgcn_mfma_f32_32x32x16_bf16(vf1, f2.v, acc0, 0, 0, 0);
        acc1 = __builtin_amdgcn_mfma_f32_32x32x16_bf16(vf2, f1.v, acc1, 0, 0, 0);
        acc1 = __builtin_amdgcn_mfma_f32_32x32x16_bf16(vf3, f2.v, acc1, 0, 0, 0);
      }

      // write next tile into the other buffer (prev readers fenced by the
      // barrier at the end of the previous iteration)
      if (more) {
        const int nb = (buf ^ 1) * 256;
        lds[nb + wKidx] = kreg;
        lds[nb + wVidx] = vreg;
      }
      __syncthreads();
      buf ^= 1;
    }

    // epilogue: O = acc / l_run
    const float inv = 1.f / l_run;
    bf16_t* yrow = y + (size_t)(b * T_SEQ + q_glob) * D_MODEL + h * HD;
    union st8 { uint2 u2; __hip_bfloat162 h2[2]; };
#pragma unroll
    for (int gg = 0; gg < 4; ++gg) {
      st8 o0, o1;
      o0.h2[0] = __float22bfloat162_rn(make_float2(acc0[4 * gg + 0] * inv, acc0[4 * gg + 1] * inv));
      o0.h2[1] = __float22bfloat162_rn(make_float2(acc0[4 * gg + 2] * inv, acc0[4 * gg + 3] * inv));
      o1.h2[0] = __float22bfloat162_rn(make_float2(acc1[4 * gg + 0] * inv, acc1[4 * gg + 1] * inv));
      o1.h2[1] = __float22bfloat162_rn(make_float2(acc1[4 * gg + 2] * inv, acc1[4 * gg + 3] * inv));
      *(uint2*)(yrow + 8 * gg + 4 * hi)      = o0.u2;
      *(uint2*)(yrow + 32 + 8 * gg + 4 * hi) = o1.u2;
    }
  }
}

// ---------------------------------------------------------------------------
extern "C" void kernel_launch(void* const* d_in, const int* in_sizes, int n_in,
                              void* d_out, int out_size, void* d_ws,
                              size_t ws_size, hipStream_t stream) {
  const float* x    = (const float*)d_in[0];
  const float* cosb = (const float*)d_in[1];
  const float* sinb = (const float*)d_in[2];
  const float* Wq   = (const float*)d_in[3];
  const float* Wk   = (const float*)d_in[4];
  const float* Wv   = (const float*)d_in[5];
  const float* Wo   = (const float*)d_in[6];
  const float* qs   = (const float*)d_in[7];
  const float* ks   = (const float*)d_in[8];
  float* out = (float*)d_out;   // reference output dtype is float32

  char* ws = (char*)d_ws;
  bf16_t* qkv = (bf16_t*)ws;                                   // 25165824 B
  bf16_t* v_t = (bf16_t*)(ws + 25165824);                      // 4194304 B
  bf16_t* y   = (bf16_t*)(ws + 25165824 + 4194304);            // 16777216 B

  gemm_bt<true, bf16_t><<<dim3(12, 64), 256, 0, stream>>>(x, Wq, Wk, Wv, qkv, LDQKV);
  rms_rope<<<dim3(8192), 256, 0, stream>>>(qkv, cosb, sinb, qs, ks);
  v_transpose<<<dim3(16, 32), 256, 0, stream>>>(qkv, v_t);
  attn<<<dim3(512), 256, 0, stream>>>(qkv, v_t, y);
  gemm_bt<false, float><<<dim3(8, 64), 256, 0, stream>>>(y, Wo, Wo, Wo, out, D_MODEL);
}